// Round 1
// baseline (1210.802 us; speedup 1.0000x reference)
//
#include <hip/hip_runtime.h>
#include <hip/hip_bf16.h>

#define NB 64
#define NN 512
#define ND 1024
#define NC 4
#define NDW 524288  // N*D, fc_w row stride

typedef __attribute__((ext_vector_type(8))) __bf16 bf16x8;
typedef __attribute__((ext_vector_type(4))) float f32x4;

__device__ __forceinline__ unsigned short f2bf(float x) {
    unsigned int u = __float_as_uint(x);
    u = (u + 0x7fffu + ((u >> 16) & 1u)) >> 16;   // RNE
    return (unsigned short)u;
}

union BF8 { bf16x8 v; unsigned short s[8]; };

__global__ __launch_bounds__(256)
void nma_init_out(float* __restrict__ out, const float* __restrict__ fcb) {
    int t = threadIdx.x;
    if (t < NB * NC) out[t] = fcb[t & 3];
}

// One block per (b, 32-row Q tile). 256 threads = 4 waves.
// Dead-path elimination: dopamine/serotonin mod is a per-row constant -> cancels
// in (ms - mean)/std. Only QK^T -> std-normalized softmax -> PV -> FC survives.
__global__ __launch_bounds__(256, 2)
void nma_attn(const float* __restrict__ Q, const float* __restrict__ K,
              const float* __restrict__ V, const int* __restrict__ eid,
              const float* __restrict__ emb, const float* __restrict__ fcw,
              float* __restrict__ out)
{
    // KV: K-chunk [512 m][32 k +8 pad] bf16 in phase 2; V^T-chunk [512 d][32 m +8 pad] in phase 4. 40 KB.
    __shared__ __align__(16) unsigned short KV[NN * 40];
    __shared__ __align__(16) unsigned short Ps[32 * 520];   // probs bf16, stride 520 (pad -> <=2-way banks)
    __shared__ float red[4][32][4];
    __shared__ float rowM[32], rowInv[32], rowRden[32];
    __shared__ float wred[4][4];

    const int tid  = threadIdx.x;
    const int w    = tid >> 6;        // wave 0..3
    const int lane = tid & 63;
    const int q    = lane >> 4;       // quad 0..3
    const int l15  = lane & 15;
    const int b    = blockIdx.y;
    const int i0   = blockIdx.x * 32;
    const size_t bOff = (size_t)b * NN * ND;

    // Hoisted A-operand row pointers (rows i0+l15 and i0+16+l15)
    const float* Qrow0 = Q + bOff + (size_t)(i0 + l15) * ND;
    const float* Qrow1 = Q + bOff + (size_t)(i0 + 16 + l15) * ND;
    const float* Erow0 = emb + (size_t)eid[i0 + l15] * ND;
    const float* Erow1 = emb + (size_t)eid[i0 + 16 + l15] * ND;

    f32x4 acc[2][8];
    #pragma unroll
    for (int it = 0; it < 2; ++it)
        #pragma unroll
        for (int mt = 0; mt < 8; ++mt)
            acc[it][mt] = (f32x4){0.f, 0.f, 0.f, 0.f};

    const int sm = tid >> 3;   // staging m-subrow 0..31
    const int sk = tid & 7;    // staging float4 col 0..7

    // ---------------- Phase 2: S = (Q+e)(K+e)^T, K staged bf16 in LDS ----------------
    for (int kc = 0; kc < 32; ++kc) {
        __syncthreads();
        {
            const int koff = kc * 32 + sk * 4;
            #pragma unroll 4
            for (int ii = 0; ii < 16; ++ii) {
                const int m = ii * 32 + sm;
                const float4 kv = *(const float4*)(K + bOff + (size_t)m * ND + koff);
                const float4 ev = *(const float4*)(emb + (size_t)eid[m] * ND + koff);
                unsigned int lo = (unsigned)f2bf(kv.x + ev.x) | ((unsigned)f2bf(kv.y + ev.y) << 16);
                unsigned int hi = (unsigned)f2bf(kv.z + ev.z) | ((unsigned)f2bf(kv.w + ev.w) << 16);
                uint2 pk; pk.x = lo; pk.y = hi;
                *(uint2*)&KV[m * 40 + sk * 4] = pk;
            }
        }
        // A fragments direct from global (redundant across waves, L1-resident)
        BF8 a0u, a1u;
        {
            const int k0 = kc * 32 + q * 8;
            float4 x0 = *(const float4*)(Qrow0 + k0);
            float4 x1 = *(const float4*)(Qrow0 + k0 + 4);
            float4 e0 = *(const float4*)(Erow0 + k0);
            float4 e1 = *(const float4*)(Erow0 + k0 + 4);
            a0u.s[0] = f2bf(x0.x + e0.x); a0u.s[1] = f2bf(x0.y + e0.y);
            a0u.s[2] = f2bf(x0.z + e0.z); a0u.s[3] = f2bf(x0.w + e0.w);
            a0u.s[4] = f2bf(x1.x + e1.x); a0u.s[5] = f2bf(x1.y + e1.y);
            a0u.s[6] = f2bf(x1.z + e1.z); a0u.s[7] = f2bf(x1.w + e1.w);
            x0 = *(const float4*)(Qrow1 + k0);
            x1 = *(const float4*)(Qrow1 + k0 + 4);
            e0 = *(const float4*)(Erow1 + k0);
            e1 = *(const float4*)(Erow1 + k0 + 4);
            a1u.s[0] = f2bf(x0.x + e0.x); a1u.s[1] = f2bf(x0.y + e0.y);
            a1u.s[2] = f2bf(x0.z + e0.z); a1u.s[3] = f2bf(x0.w + e0.w);
            a1u.s[4] = f2bf(x1.x + e1.x); a1u.s[5] = f2bf(x1.y + e1.y);
            a1u.s[6] = f2bf(x1.z + e1.z); a1u.s[7] = f2bf(x1.w + e1.w);
        }
        __syncthreads();
        const int mrow = w * 128 + l15;
        #pragma unroll
        for (int mt = 0; mt < 8; ++mt) {
            bf16x8 bf = *(const bf16x8*)&KV[(mrow + mt * 16) * 40 + q * 8];
            acc[0][mt] = __builtin_amdgcn_mfma_f32_16x16x32_bf16(a0u.v, bf, acc[0][mt], 0, 0, 0);
            acc[1][mt] = __builtin_amdgcn_mfma_f32_16x16x32_bf16(a1u.v, bf, acc[1][mt], 0, 0, 0);
        }
    }

    // ---------------- Phase 3: scale, exact row stats (mean, ddof=1 std, max), softmax ----------------
    const float SC = 0.03125f; // 1/sqrt(1024)
    #pragma unroll
    for (int it = 0; it < 2; ++it)
        #pragma unroll
        for (int mt = 0; mt < 8; ++mt) {
            acc[it][mt][0] *= SC; acc[it][mt][1] *= SC;
            acc[it][mt][2] *= SC; acc[it][mt][3] *= SC;
        }
    // C-layout: value at (row i = it*16 + q*4 + r, col m = w*128 + mt*16 + l15)
    float ssum[2][4], ssq[2][4], smax[2][4];
    #pragma unroll
    for (int it = 0; it < 2; ++it)
        #pragma unroll
        for (int r = 0; r < 4; ++r) {
            float s = 0.f, s2 = 0.f, mx = -3.4e38f;
            #pragma unroll
            for (int mt = 0; mt < 8; ++mt) {
                float v = acc[it][mt][r];
                s += v; s2 += v * v; mx = fmaxf(mx, v);
            }
            #pragma unroll
            for (int d = 1; d < 16; d <<= 1) {
                s  += __shfl_xor(s, d);
                s2 += __shfl_xor(s2, d);
                mx  = fmaxf(mx, __shfl_xor(mx, d));
            }
            ssum[it][r] = s; ssq[it][r] = s2; smax[it][r] = mx;
        }
    if (l15 == 0) {
        #pragma unroll
        for (int it = 0; it < 2; ++it)
            #pragma unroll
            for (int r = 0; r < 4; ++r) {
                int i = it * 16 + q * 4 + r;
                red[w][i][0] = ssum[it][r];
                red[w][i][1] = ssq[it][r];
                red[w][i][2] = smax[it][r];
            }
    }
    __syncthreads();
    if (tid < 32) {
        float s  = red[0][tid][0] + red[1][tid][0] + red[2][tid][0] + red[3][tid][0];
        float s2 = red[0][tid][1] + red[1][tid][1] + red[2][tid][1] + red[3][tid][1];
        float mx = fmaxf(fmaxf(red[0][tid][2], red[1][tid][2]),
                         fmaxf(red[2][tid][2], red[3][tid][2]));
        float mu  = s * (1.f / 512.f);
        float var = fmaxf((s2 - s * mu) * (1.f / 511.f), 0.f);
        float sd  = sqrtf(var);
        rowM[tid]   = mx;
        rowInv[tid] = 1.f / (sd + 1e-6f);
    }
    __syncthreads();
    float dsum[2][4];
    #pragma unroll
    for (int it = 0; it < 2; ++it)
        #pragma unroll
        for (int r = 0; r < 4; ++r) {
            int i = it * 16 + q * 4 + r;
            float M = rowM[i], inv = rowInv[i];
            float s = 0.f;
            #pragma unroll
            for (int mt = 0; mt < 8; ++mt) {
                float e = __expf((acc[it][mt][r] - M) * inv);  // == exp(z - zmax)
                acc[it][mt][r] = e; s += e;
            }
            #pragma unroll
            for (int d = 1; d < 16; d <<= 1) s += __shfl_xor(s, d);
            dsum[it][r] = s;
        }
    if (l15 == 0) {
        #pragma unroll
        for (int it = 0; it < 2; ++it)
            #pragma unroll
            for (int r = 0; r < 4; ++r)
                red[w][it * 16 + q * 4 + r][0] = dsum[it][r];
    }
    __syncthreads();
    if (tid < 32)
        rowRden[tid] = 1.f / (red[0][tid][0] + red[1][tid][0] + red[2][tid][0] + red[3][tid][0]);
    __syncthreads();
    // P bf16 -> LDS (C-layout -> A-layout transform through LDS)
    #pragma unroll
    for (int it = 0; it < 2; ++it)
        #pragma unroll
        for (int r = 0; r < 4; ++r) {
            int i = it * 16 + q * 4 + r;
            float rd = rowRden[i];
            #pragma unroll
            for (int mt = 0; mt < 8; ++mt) {
                int m = w * 128 + mt * 16 + l15;
                Ps[i * 520 + m] = f2bf(acc[it][mt][r] * rd);
            }
        }

    // ---------------- Phase 4: O = P (V+e); V staged transposed; fused FC epilogue ----------------
    float pc0 = 0.f, pc1 = 0.f, pc2 = 0.f, pc3 = 0.f;
    const int vm   = tid >> 3;  // m-subrow 0..31 (coalesced global reads)
    const int vseg = tid & 7;   // d-segment 0..7
    for (int h = 0; h < 2; ++h) {
        f32x4 oacc[2][8];
        #pragma unroll
        for (int it = 0; it < 2; ++it)
            #pragma unroll
            for (int dt = 0; dt < 8; ++dt)
                oacc[it][dt] = (f32x4){0.f, 0.f, 0.f, 0.f};
        for (int mc = 0; mc < 16; ++mc) {
            __syncthreads();
            {
                const int m = mc * 32 + vm;
                const float* Vrow = V + bOff + (size_t)m * ND + h * 512;
                const float* Er   = emb + (size_t)eid[m] * ND + h * 512;
                #pragma unroll 4
                for (int dd = 0; dd < 16; ++dd) {
                    const int d0 = dd * 32 + vseg * 4;
                    float4 v  = *(const float4*)(Vrow + d0);
                    float4 ev = *(const float4*)(Er + d0);
                    KV[(d0 + 0) * 40 + vm] = f2bf(v.x + ev.x);
                    KV[(d0 + 1) * 40 + vm] = f2bf(v.y + ev.y);
                    KV[(d0 + 2) * 40 + vm] = f2bf(v.z + ev.z);
                    KV[(d0 + 3) * 40 + vm] = f2bf(v.w + ev.w);
                }
            }
            __syncthreads();
            bf16x8 p0 = *(const bf16x8*)&Ps[l15 * 520 + mc * 32 + q * 8];
            bf16x8 p1 = *(const bf16x8*)&Ps[(16 + l15) * 520 + mc * 32 + q * 8];
            const int drow = w * 128 + l15;
            #pragma unroll
            for (int dt = 0; dt < 8; ++dt) {
                bf16x8 bf = *(const bf16x8*)&KV[(drow + dt * 16) * 40 + q * 8];
                oacc[0][dt] = __builtin_amdgcn_mfma_f32_16x16x32_bf16(p0, bf, oacc[0][dt], 0, 0, 0);
                oacc[1][dt] = __builtin_amdgcn_mfma_f32_16x16x32_bf16(p1, bf, oacc[1][dt], 0, 0, 0);
            }
        }
        // fused FC partials for this d-half
        #pragma unroll
        for (int it = 0; it < 2; ++it)
            #pragma unroll
            for (int dt = 0; dt < 8; ++dt) {
                const int dglob = h * 512 + w * 128 + dt * 16 + l15;
                #pragma unroll
                for (int r = 0; r < 4; ++r) {
                    const int iglob = i0 + it * 16 + q * 4 + r;
                    const size_t widx = (size_t)iglob * ND + dglob;
                    const float ov = oacc[it][dt][r];
                    pc0 += ov * fcw[widx];
                    pc1 += ov * fcw[(size_t)NDW + widx];
                    pc2 += ov * fcw[2 * (size_t)NDW + widx];
                    pc3 += ov * fcw[3 * (size_t)NDW + widx];
                }
            }
    }
    #pragma unroll
    for (int d = 1; d < 64; d <<= 1) {
        pc0 += __shfl_xor(pc0, d); pc1 += __shfl_xor(pc1, d);
        pc2 += __shfl_xor(pc2, d); pc3 += __shfl_xor(pc3, d);
    }
    if (lane == 0) { wred[w][0] = pc0; wred[w][1] = pc1; wred[w][2] = pc2; wred[w][3] = pc3; }
    __syncthreads();
    if (tid < 4) {
        float v = wred[0][tid] + wred[1][tid] + wred[2][tid] + wred[3][tid];
        atomicAdd(&out[b * NC + tid], v);
    }
}

extern "C" void kernel_launch(void* const* d_in, const int* in_sizes, int n_in,
                              void* d_out, int out_size, void* d_ws, size_t ws_size,
                              hipStream_t stream) {
    (void)in_sizes; (void)n_in; (void)d_ws; (void)ws_size; (void)out_size;
    const float* Q   = (const float*)d_in[0];
    const float* K   = (const float*)d_in[1];
    const float* V   = (const float*)d_in[2];
    const int*   eid = (const int*)d_in[3];
    const float* emb = (const float*)d_in[4];
    const float* fcw = (const float*)d_in[15];
    const float* fcb = (const float*)d_in[16];
    float* out = (float*)d_out;

    nma_init_out<<<dim3(1), dim3(256), 0, stream>>>(out, fcb);
    nma_attn<<<dim3(16, 64), dim3(256), 0, stream>>>(Q, K, V, eid, emb, fcw, out);
}

// Round 2
// 742.854 us; speedup vs baseline: 1.6299x; 1.6299x over previous
//
#include <hip/hip_runtime.h>

#define NN 512
#define ND 1024
#define NDW 524288   // N*D
#define NBATCH 64

typedef __attribute__((ext_vector_type(8))) __bf16 bf16x8;
typedef __attribute__((ext_vector_type(4))) float f32x4;
typedef unsigned short u16;
typedef unsigned int u32;

__device__ __forceinline__ u16 f2bf(float x) {
    u32 u = __float_as_uint(x);
    u = (u + 0x7fffu + ((u >> 16) & 1u)) >> 16;   // RNE
    return (u16)u;
}
__device__ __forceinline__ float bf2f(u16 x) {
    return __uint_as_float(((u32)x) << 16);
}

union BF8 { bf16x8 v; u16 s[8]; };

// async global->LDS DMA, 16B per lane; LDS dest = wave-uniform base + lane*16
__device__ __forceinline__ void dma16(const u16* g, const u16* l) {
    __builtin_amdgcn_global_load_lds(
        (const __attribute__((address_space(1))) u32*)(uintptr_t)g,
        (__attribute__((address_space(3))) u32*)(u32)(uintptr_t)l,
        16, 0, 0);
}

__global__ __launch_bounds__(256)
void nma_init_out(float* __restrict__ out, const float* __restrict__ fcb) {
    int t = threadIdx.x;
    if (t < NBATCH * 4) out[t] = fcb[t & 3];
}

// Ke = bf16(K + emb[eid]) row-major [B,N,D]
__global__ __launch_bounds__(256)
void prep_ke(const float* __restrict__ K, const int* __restrict__ eid,
             const float* __restrict__ emb, u16* __restrict__ Ke) {
    size_t f = ((size_t)blockIdx.x * 256 + threadIdx.x) * 8;
    int n = (int)((f >> 10) & (NN - 1));
    int col = (int)(f & (ND - 1));
    const float* kp = K + f;
    const float* ep = emb + (size_t)eid[n] * ND + col;
    float4 k0 = *(const float4*)kp, k1 = *(const float4*)(kp + 4);
    float4 e0 = *(const float4*)ep, e1 = *(const float4*)(ep + 4);
    union { uint4 q; u16 s[8]; } o;
    o.s[0]=f2bf(k0.x+e0.x); o.s[1]=f2bf(k0.y+e0.y); o.s[2]=f2bf(k0.z+e0.z); o.s[3]=f2bf(k0.w+e0.w);
    o.s[4]=f2bf(k1.x+e1.x); o.s[5]=f2bf(k1.y+e1.y); o.s[6]=f2bf(k1.z+e1.z); o.s[7]=f2bf(k1.w+e1.w);
    *(uint4*)(Ke + f) = o.q;
}

// VT[b,d,n] = bf16(V[b,n,d] + emb[eid[n],d]) — 64x64 LDS tile transpose
__global__ __launch_bounds__(256)
void prep_vt(const float* __restrict__ V, const int* __restrict__ eid,
             const float* __restrict__ emb, u16* __restrict__ VT) {
    __shared__ u16 T[64 * 72];
    const int tid = threadIdx.x;
    const int b = blockIdx.z, d0 = blockIdx.y * 64, n0 = blockIdx.x * 64;
    {
        const int r = tid >> 2, cs = (tid & 3) * 16;
        const int n = n0 + r;
        const float* vp = V + ((size_t)b * NN + n) * ND + d0 + cs;
        const float* ep = emb + (size_t)eid[n] * ND + d0 + cs;
        #pragma unroll
        for (int j = 0; j < 4; ++j) {
            float4 v = *(const float4*)(vp + j * 4);
            float4 e = *(const float4*)(ep + j * 4);
            T[(cs + j*4 + 0) * 72 + r] = f2bf(v.x + e.x);
            T[(cs + j*4 + 1) * 72 + r] = f2bf(v.y + e.y);
            T[(cs + j*4 + 2) * 72 + r] = f2bf(v.z + e.z);
            T[(cs + j*4 + 3) * 72 + r] = f2bf(v.w + e.w);
        }
    }
    __syncthreads();
    {
        const int dr = tid >> 2, ms = (tid & 3) * 16;
        u16* dst = VT + ((size_t)b * ND + d0 + dr) * NN + n0 + ms;
        *(uint4*)dst       = *(const uint4*)&T[dr * 72 + ms];
        *(uint4*)(dst + 8) = *(const uint4*)&T[dr * 72 + ms + 8];
    }
}

// One block per (b, 32-row Q tile). Dead-path: neuromod term is per-row const,
// cancels in (ms-mean)/std -> only QK^T -> z-softmax -> PV survives.
// XCD swizzle: b = (bid&7) + 8*(bid>>7) so all 16 tiles of a batch share an XCD L2.
__global__ __launch_bounds__(256, 2)
void nma_attn(const float* __restrict__ Q, const int* __restrict__ eid,
              const float* __restrict__ emb, const u16* __restrict__ Ke,
              const u16* __restrict__ VT, u16* __restrict__ O)
{
    __shared__ __align__(16) u16 KV[NN * 32];     // 32KB: DMA chunk [512 rows][32 cols] bf16
    __shared__ __align__(16) u16 Ps[32 * 520];    // probs bf16
    __shared__ float red[4][32][4];
    __shared__ float rowM[32], rowInv[32], rowRden[32];

    const int tid  = threadIdx.x;
    const int w    = tid >> 6;
    const int lane = tid & 63;
    const int q    = lane >> 4;
    const int l15  = lane & 15;
    const int bid  = blockIdx.x;
    const int jj   = bid >> 3;
    const int b    = (bid & 7) + ((jj >> 4) << 3);
    const int i0   = (jj & 15) * 32;
    const size_t bOff = (size_t)b * NN * ND;

    const float* Qrow0 = Q + bOff + (size_t)(i0 + l15) * ND;
    const float* Qrow1 = Q + bOff + (size_t)(i0 + 16 + l15) * ND;
    const float* Erow0 = emb + (size_t)eid[i0 + l15] * ND;
    const float* Erow1 = emb + (size_t)eid[i0 + 16 + l15] * ND;

    const u16* KeB = Ke + bOff;
    const u16* VTB = VT + (size_t)b * ND * NN;
    const int liw = w * 64 + lane;

    f32x4 acc[2][8];
    #pragma unroll
    for (int it = 0; it < 2; ++it)
        #pragma unroll
        for (int mt = 0; mt < 8; ++mt)
            acc[it][mt] = (f32x4){0.f, 0.f, 0.f, 0.f};

    // ---- Phase 2: S = Qe * Ke^T ----
    for (int kc = 0; kc < 32; ++kc) {
        __syncthreads();
        #pragma unroll
        for (int ii = 0; ii < 8; ++ii) {
            const int li = ii * 256 + liw;
            const int m = li >> 2, seg = li & 3;
            dma16(KeB + (size_t)m * ND + kc * 32 + seg * 8,
                  &KV[(size_t)(ii * 256 + w * 64) * 8]);
        }
        BF8 a0u, a1u;
        {
            const int k0 = kc * 32 + q * 8;
            float4 x0 = *(const float4*)(Qrow0 + k0);
            float4 x1 = *(const float4*)(Qrow0 + k0 + 4);
            float4 e0 = *(const float4*)(Erow0 + k0);
            float4 e1 = *(const float4*)(Erow0 + k0 + 4);
            a0u.s[0] = f2bf(x0.x + e0.x); a0u.s[1] = f2bf(x0.y + e0.y);
            a0u.s[2] = f2bf(x0.z + e0.z); a0u.s[3] = f2bf(x0.w + e0.w);
            a0u.s[4] = f2bf(x1.x + e1.x); a0u.s[5] = f2bf(x1.y + e1.y);
            a0u.s[6] = f2bf(x1.z + e1.z); a0u.s[7] = f2bf(x1.w + e1.w);
            x0 = *(const float4*)(Qrow1 + k0);
            x1 = *(const float4*)(Qrow1 + k0 + 4);
            e0 = *(const float4*)(Erow1 + k0);
            e1 = *(const float4*)(Erow1 + k0 + 4);
            a1u.s[0] = f2bf(x0.x + e0.x); a1u.s[1] = f2bf(x0.y + e0.y);
            a1u.s[2] = f2bf(x0.z + e0.z); a1u.s[3] = f2bf(x0.w + e0.w);
            a1u.s[4] = f2bf(x1.x + e1.x); a1u.s[5] = f2bf(x1.y + e1.y);
            a1u.s[6] = f2bf(x1.z + e1.z); a1u.s[7] = f2bf(x1.w + e1.w);
        }
        __syncthreads();
        #pragma unroll
        for (int mt = 0; mt < 8; ++mt) {
            bf16x8 bf = *(const bf16x8*)&KV[(w * 128 + mt * 16 + l15) * 32 + q * 8];
            acc[0][mt] = __builtin_amdgcn_mfma_f32_16x16x32_bf16(a0u.v, bf, acc[0][mt], 0, 0, 0);
            acc[1][mt] = __builtin_amdgcn_mfma_f32_16x16x32_bf16(a1u.v, bf, acc[1][mt], 0, 0, 0);
        }
    }

    // ---- Phase 3: exact row stats (mean, ddof=1 std, max), softmax(z) ----
    const float SC = 0.03125f;
    #pragma unroll
    for (int it = 0; it < 2; ++it)
        #pragma unroll
        for (int mt = 0; mt < 8; ++mt) {
            acc[it][mt][0] *= SC; acc[it][mt][1] *= SC;
            acc[it][mt][2] *= SC; acc[it][mt][3] *= SC;
        }
    float ssum[2][4], ssq[2][4], smax[2][4];
    #pragma unroll
    for (int it = 0; it < 2; ++it)
        #pragma unroll
        for (int r = 0; r < 4; ++r) {
            float s = 0.f, s2 = 0.f, mx = -3.4e38f;
            #pragma unroll
            for (int mt = 0; mt < 8; ++mt) {
                float v = acc[it][mt][r];
                s += v; s2 += v * v; mx = fmaxf(mx, v);
            }
            #pragma unroll
            for (int d = 1; d < 16; d <<= 1) {
                s  += __shfl_xor(s, d);
                s2 += __shfl_xor(s2, d);
                mx  = fmaxf(mx, __shfl_xor(mx, d));
            }
            ssum[it][r] = s; ssq[it][r] = s2; smax[it][r] = mx;
        }
    if (l15 == 0) {
        #pragma unroll
        for (int it = 0; it < 2; ++it)
            #pragma unroll
            for (int r = 0; r < 4; ++r) {
                int i = it * 16 + q * 4 + r;
                red[w][i][0] = ssum[it][r];
                red[w][i][1] = ssq[it][r];
                red[w][i][2] = smax[it][r];
            }
    }
    __syncthreads();
    if (tid < 32) {
        float s  = red[0][tid][0] + red[1][tid][0] + red[2][tid][0] + red[3][tid][0];
        float s2 = red[0][tid][1] + red[1][tid][1] + red[2][tid][1] + red[3][tid][1];
        float mx = fmaxf(fmaxf(red[0][tid][2], red[1][tid][2]),
                         fmaxf(red[2][tid][2], red[3][tid][2]));
        float mu  = s * (1.f / 512.f);
        float var = fmaxf((s2 - s * mu) * (1.f / 511.f), 0.f);
        float sd  = sqrtf(var);
        rowM[tid]   = mx;
        rowInv[tid] = 1.f / (sd + 1e-6f);
    }
    __syncthreads();
    float dsum[2][4];
    #pragma unroll
    for (int it = 0; it < 2; ++it)
        #pragma unroll
        for (int r = 0; r < 4; ++r) {
            int i = it * 16 + q * 4 + r;
            float M = rowM[i], inv = rowInv[i];
            float s = 0.f;
            #pragma unroll
            for (int mt = 0; mt < 8; ++mt) {
                float e = __expf((acc[it][mt][r] - M) * inv);
                acc[it][mt][r] = e; s += e;
            }
            #pragma unroll
            for (int d = 1; d < 16; d <<= 1) s += __shfl_xor(s, d);
            dsum[it][r] = s;
        }
    if (l15 == 0) {
        #pragma unroll
        for (int it = 0; it < 2; ++it)
            #pragma unroll
            for (int r = 0; r < 4; ++r)
                red[w][it * 16 + q * 4 + r][0] = dsum[it][r];
    }
    __syncthreads();
    if (tid < 32)
        rowRden[tid] = 1.f / (red[0][tid][0] + red[1][tid][0] + red[2][tid][0] + red[3][tid][0]);
    __syncthreads();
    #pragma unroll
    for (int it = 0; it < 2; ++it)
        #pragma unroll
        for (int r = 0; r < 4; ++r) {
            int i = it * 16 + q * 4 + r;
            float rd = rowRden[i];
            #pragma unroll
            for (int mt = 0; mt < 8; ++mt) {
                int m = w * 128 + mt * 16 + l15;
                Ps[i * 520 + m] = f2bf(acc[it][mt][r] * rd);
            }
        }

    // ---- Phase 4: O = P * Ve via VT DMA chunks [512 d][32 m] ----
    for (int h = 0; h < 2; ++h) {
        f32x4 oacc[2][8];
        #pragma unroll
        for (int it = 0; it < 2; ++it)
            #pragma unroll
            for (int dt = 0; dt < 8; ++dt)
                oacc[it][dt] = (f32x4){0.f, 0.f, 0.f, 0.f};
        for (int mc = 0; mc < 16; ++mc) {
            __syncthreads();
            #pragma unroll
            for (int ii = 0; ii < 8; ++ii) {
                const int li = ii * 256 + liw;
                const int r = li >> 2, seg = li & 3;
                dma16(VTB + (size_t)(h * 512 + r) * NN + mc * 32 + seg * 8,
                      &KV[(size_t)(ii * 256 + w * 64) * 8]);
            }
            __syncthreads();
            bf16x8 p0 = *(const bf16x8*)&Ps[l15 * 520 + mc * 32 + q * 8];
            bf16x8 p1 = *(const bf16x8*)&Ps[(16 + l15) * 520 + mc * 32 + q * 8];
            #pragma unroll
            for (int dt = 0; dt < 8; ++dt) {
                bf16x8 bf = *(const bf16x8*)&KV[(w * 128 + dt * 16 + l15) * 32 + q * 8];
                oacc[0][dt] = __builtin_amdgcn_mfma_f32_16x16x32_bf16(p0, bf, oacc[0][dt], 0, 0, 0);
                oacc[1][dt] = __builtin_amdgcn_mfma_f32_16x16x32_bf16(p1, bf, oacc[1][dt], 0, 0, 0);
            }
        }
        #pragma unroll
        for (int it = 0; it < 2; ++it)
            #pragma unroll
            for (int dt = 0; dt < 8; ++dt) {
                const int dglob = h * 512 + w * 128 + dt * 16 + l15;
                #pragma unroll
                for (int r = 0; r < 4; ++r) {
                    const int iglob = i0 + it * 16 + q * 4 + r;
                    O[bOff + (size_t)iglob * ND + dglob] = f2bf(oacc[it][dt][r]);
                }
            }
    }
}

// out[b,c] += sum over a 1024-wide slice of O[b,:]*fcw[c,:]; fcw/O streamed once.
__global__ __launch_bounds__(256)
void fc_red(const u16* __restrict__ O, const float* __restrict__ fcw,
            float* __restrict__ out)
{
    __shared__ __align__(16) u16 Osh[64 * 264];
    __shared__ __align__(16) float Fsh[4 * 260];
    const int tid = threadIdx.x;
    const size_t nbase = (size_t)blockIdx.x * 1024;
    const int b = tid >> 2, c = tid & 3;
    float sum = 0.f;
    for (int ch = 0; ch < 4; ++ch) {
        __syncthreads();
        #pragma unroll
        for (int ii = 0; ii < 8; ++ii) {
            int si = ii * 256 + tid;
            int row = si >> 5, col8 = (si & 31) * 8;
            *(uint4*)&Osh[row * 264 + col8] =
                *(const uint4*)(O + (size_t)row * NDW + nbase + ch * 256 + col8);
        }
        {
            int cc = tid >> 6, n4 = (tid & 63) * 4;
            *(float4*)&Fsh[cc * 260 + n4] =
                *(const float4*)(fcw + (size_t)cc * NDW + nbase + ch * 256 + n4);
        }
        __syncthreads();
        #pragma unroll 4
        for (int n8 = 0; n8 < 32; ++n8) {
            union { uint4 v; u16 s[8]; } o4;
            o4.v = *(const uint4*)&Osh[b * 264 + n8 * 8];
            float4 f0 = *(const float4*)&Fsh[c * 260 + n8 * 8];
            float4 f1 = *(const float4*)&Fsh[c * 260 + n8 * 8 + 4];
            sum += bf2f(o4.s[0]) * f0.x + bf2f(o4.s[1]) * f0.y
                 + bf2f(o4.s[2]) * f0.z + bf2f(o4.s[3]) * f0.w
                 + bf2f(o4.s[4]) * f1.x + bf2f(o4.s[5]) * f1.y
                 + bf2f(o4.s[6]) * f1.z + bf2f(o4.s[7]) * f1.w;
        }
    }
    atomicAdd(&out[b * 4 + c], sum);
}

extern "C" void kernel_launch(void* const* d_in, const int* in_sizes, int n_in,
                              void* d_out, int out_size, void* d_ws, size_t ws_size,
                              hipStream_t stream) {
    (void)in_sizes; (void)n_in; (void)ws_size; (void)out_size;
    const float* Q   = (const float*)d_in[0];
    const float* K   = (const float*)d_in[1];
    const float* V   = (const float*)d_in[2];
    const int*   eid = (const int*)d_in[3];
    const float* emb = (const float*)d_in[4];
    const float* fcw = (const float*)d_in[15];
    const float* fcb = (const float*)d_in[16];
    float* out = (float*)d_out;

    u16* Ke = (u16*)d_ws;
    u16* VT = Ke + (size_t)NBATCH * NN * ND;   // +64MB
    u16* O  = VT + (size_t)NBATCH * NN * ND;   // +64MB (total ws use: 192MB)

    nma_init_out<<<dim3(1), dim3(256), 0, stream>>>(out, fcb);
    prep_ke<<<dim3(16384), dim3(256), 0, stream>>>(K, eid, emb, Ke);
    prep_vt<<<dim3(8, 16, 64), dim3(256), 0, stream>>>(V, eid, emb, VT);
    nma_attn<<<dim3(1024), dim3(256), 0, stream>>>(Q, eid, emb, Ke, VT, O);
    fc_red<<<dim3(512), dim3(256), 0, stream>>>(O, fcw, out);
}